// Round 5
// baseline (192.509 us; speedup 1.0000x reference)
//
#include <hip/hip_runtime.h>

#define IMG 224
#define HW (IMG * IMG)
#define TLX 32                 // tile extent along x (slow pixel coord, LDS cols)
#define TLY 16                 // tile extent along y (fast pixel coord, LDS rows)
#define PAD 4
#define COLS (TLX + 2 * PAD)   // 40 staged cols (x axis)
#define ROWS (TLY + 2 * PAD)   // 24 staged rows (y axis)
#define RSA 41                 // A-table row stride in float2 units (odd)
#define TABA (ROWS * RSA)      // 984 float2 per image (ch0,ch1 packed)
#define RSB 44                 // B-table row stride in floats (mult of 4)
#define TABB (ROWS * RSB)      // 1056 floats per image (ch2)

__global__ __launch_bounds__(256, 6) void vm_kernel(
    const float* __restrict__ im1, const float* __restrict__ im2,
    const float* __restrict__ C, const float* __restrict__ M1,
    const float* __restrict__ M2, float* __restrict__ out)
{
    // Packed-pair tiles, 24x40 staged region: 2*984*8 + 2*1056*4 = 24,192 B
    // -> 6 blocks/CU (24 waves resident) for latency hiding.
    __shared__ float2 tabA[2 * TABA];
    __shared__ float  tabB[2 * TABB];

    const int n    = blockIdx.y;
    const int tile = blockIdx.x;           // 0..97
    const int x0   = (tile / 14) * TLX;    // 7 x-tiles
    const int y0   = (tile % 14) * TLY;    // 14 y-tiles
    const int t    = threadIdx.x;
    const int xlo  = x0 - PAD;
    const int ylo  = y0 - PAD;
    const int gbase = xlo + IMG * ylo;     // flat index of staged origin

    const float* i1n = im1 + (size_t)n * 3 * HW;
    const float* i2n = im2 + (size_t)n * 3 * HW;
    const float* Cn  = C  + (size_t)n * 2 * HW;
    const float* M1n = M1 + (size_t)n * HW;
    const float* M2n = M2 + (size_t)n * HW;

    // ---- C/M first: independent of staging, overlap their latency under it.
    //      Thread owns 2 consecutive ty -> float2 coalesced.
    const int tx  = t >> 3;                // 0..31 (x offset in tile)
    const int ty0 = (t & 7) * 2;           // 0,2,..,14 (y offset base)
    const int p   = (x0 + tx) * IMG + (y0 + ty0);

    const float2 c0v = *(const float2*)(Cn + p);
    const float2 c1v = *(const float2*)(Cn + HW + p);
    const float2 m1v = *(const float2*)(M1n + p);
    const float2 m2v = *(const float2*)(M2n + p);

    // ---- stage both images: 240 units per image (24 rows x 10 units of 4
    //      consecutive-x pixels). One unit per thread per image (t < 240):
    //      3 float4 global loads, 4 ds_write_b64 (A) + 1 ds_write_b128 (B).
#pragma unroll
    for (int img = 0; img < 2; ++img) {
        const float* src = img ? i2n : i1n;
        float2* TA = tabA + img * TABA;
        float*  TB = tabB + img * TABB;
        if (t < 240) {
            int r = t / 10, s = t - r * 10;
            int gi = gbase + IMG * r + 4 * s;
            float4 a, b, c;
            if (gi >= 0 && gi <= HW - 4) {
                a = *(const float4*)(src + gi);
                b = *(const float4*)(src + HW + gi);
                c = *(const float4*)(src + 2 * HW + gi);
            } else {                    // flat-clamp edge rows (rare tiles)
#pragma unroll
                for (int i = 0; i < 4; ++i) {
                    int g = min(max(gi + i, 0), HW - 1);
                    ((float*)&a)[i] = src[g];
                    ((float*)&b)[i] = src[HW + g];
                    ((float*)&c)[i] = src[2 * HW + g];
                }
            }
            float2* dA = TA + r * RSA + 4 * s;
            dA[0] = make_float2(a.x, b.x);
            dA[1] = make_float2(a.y, b.y);
            dA[2] = make_float2(a.z, b.z);
            dA[3] = make_float2(a.w, b.w);
            *(float4*)(TB + r * RSB + 4 * s) = c;   // (r*44+4s) % 4 == 0
        }
    }

    __syncthreads();                       // the ONLY barrier

    // ---- phase 2: 2 pixels per thread; per tap one ds_read_b64 (ch0,ch1)
    //      + one ds_read_b32 (ch2). Store as 3 float2.
    const float xf = (float)(x0 + tx);
    float acc0[2], acc1[2], acc2[2];

#pragma unroll
    for (int i = 0; i < 2; ++i) {
        const float yf  = (float)(y0 + ty0 + i);
        const float cc0 = ((const float*)&c0v)[i];
        const float cc1 = ((const float*)&c1v)[i];
        const float m1i = ((const float*)&m1v)[i];
        const float m2i = ((const float*)&m2v)[i];
        float r0c, r1c, r2c;

        {   // +C on im1
            float px = xf + cc0, py = yf + cc1;
            float fx = floorf(px), cx = ceilf(px);
            float fy = floorf(py), cy = ceilf(py);
            float wfx = 1.0f - (px - fx), wcx = 1.0f - (cx - px);
            float wfy = 1.0f - (py - fy), wcy = 1.0f - (cy - py);
            float w0 = wfx * wfy, w1 = wcx * wfy;
            float w2 = wfx * wcy, w3 = wcx * wcy;
            int gx0 = (int)fx, gy0 = (int)fy;
            int dx = (int)cx - gx0, dy = (int)cy - gy0;
            int q0 = gx0 - xlo, r0 = gy0 - ylo;
            int in = (q0 >= 0) & (q0 + dx <= COLS - 1) &
                     (r0 >= 0) & (r0 + dy <= ROWS - 1);
            if (__all(in)) {
                int oA = r0 * RSA + q0;
                int oB = r0 * RSB + q0;
                float2 a0 = tabA[oA],            a1 = tabA[oA + dx];
                float2 a2 = tabA[oA + dy * RSA], a3 = tabA[oA + dx + dy * RSA];
                float  b0 = tabB[oB],            b1 = tabB[oB + dx];
                float  b2 = tabB[oB + dy * RSB], b3 = tabB[oB + dx + dy * RSB];
                r0c = m1i * (w0 * a0.x + w1 * a1.x + w2 * a2.x + w3 * a3.x);
                r1c = m1i * (w0 * a0.y + w1 * a1.y + w2 * a2.y + w3 * a3.y);
                r2c = m1i * (w0 * b0   + w1 * b1   + w2 * b2   + w3 * b3);
            } else {   // rare: displacement beyond PAD -> global clamped gather
                int i0 = min(max(gx0      + IMG * gy0,        0), HW - 1);
                int i1 = min(max(gx0 + dx + IMG * gy0,        0), HW - 1);
                int i2 = min(max(gx0      + IMG * (gy0 + dy), 0), HW - 1);
                int i3 = min(max(gx0 + dx + IMG * (gy0 + dy), 0), HW - 1);
                r0c = m1i * (w0 * i1n[i0] + w1 * i1n[i1] +
                             w2 * i1n[i2] + w3 * i1n[i3]);
                r1c = m1i * (w0 * i1n[HW + i0] + w1 * i1n[HW + i1] +
                             w2 * i1n[HW + i2] + w3 * i1n[HW + i3]);
                r2c = m1i * (w0 * i1n[2 * HW + i0] + w1 * i1n[2 * HW + i1] +
                             w2 * i1n[2 * HW + i2] + w3 * i1n[2 * HW + i3]);
            }
        }
        {   // -C on im2
            float px = xf - cc0, py = yf - cc1;
            float fx = floorf(px), cx = ceilf(px);
            float fy = floorf(py), cy = ceilf(py);
            float wfx = 1.0f - (px - fx), wcx = 1.0f - (cx - px);
            float wfy = 1.0f - (py - fy), wcy = 1.0f - (cy - py);
            float w0 = wfx * wfy, w1 = wcx * wfy;
            float w2 = wfx * wcy, w3 = wcx * wcy;
            int gx0 = (int)fx, gy0 = (int)fy;
            int dx = (int)cx - gx0, dy = (int)cy - gy0;
            int q0 = gx0 - xlo, r0 = gy0 - ylo;
            int in = (q0 >= 0) & (q0 + dx <= COLS - 1) &
                     (r0 >= 0) & (r0 + dy <= ROWS - 1);
            if (__all(in)) {
                const float2* TA = tabA + TABA;
                const float*  TB = tabB + TABB;
                int oA = r0 * RSA + q0;
                int oB = r0 * RSB + q0;
                float2 a0 = TA[oA],            a1 = TA[oA + dx];
                float2 a2 = TA[oA + dy * RSA], a3 = TA[oA + dx + dy * RSA];
                float  b0 = TB[oB],            b1 = TB[oB + dx];
                float  b2 = TB[oB + dy * RSB], b3 = TB[oB + dx + dy * RSB];
                r0c += m2i * (w0 * a0.x + w1 * a1.x + w2 * a2.x + w3 * a3.x);
                r1c += m2i * (w0 * a0.y + w1 * a1.y + w2 * a2.y + w3 * a3.y);
                r2c += m2i * (w0 * b0   + w1 * b1   + w2 * b2   + w3 * b3);
            } else {
                int i0 = min(max(gx0      + IMG * gy0,        0), HW - 1);
                int i1 = min(max(gx0 + dx + IMG * gy0,        0), HW - 1);
                int i2 = min(max(gx0      + IMG * (gy0 + dy), 0), HW - 1);
                int i3 = min(max(gx0 + dx + IMG * (gy0 + dy), 0), HW - 1);
                r0c += m2i * (w0 * i2n[i0] + w1 * i2n[i1] +
                              w2 * i2n[i2] + w3 * i2n[i3]);
                r1c += m2i * (w0 * i2n[HW + i0] + w1 * i2n[HW + i1] +
                              w2 * i2n[HW + i2] + w3 * i2n[HW + i3]);
                r2c += m2i * (w0 * i2n[2 * HW + i0] + w1 * i2n[2 * HW + i1] +
                              w2 * i2n[2 * HW + i2] + w3 * i2n[2 * HW + i3]);
            }
        }
        acc0[i] = r0c; acc1[i] = r1c; acc2[i] = r2c;
    }

    // coalesced float2 stores (lanes consecutive in ty0 -> contiguous)
    float* on = out + (size_t)n * 3 * HW;
    *(float2*)(on + p)          = make_float2(acc0[0], acc0[1]);
    *(float2*)(on + HW + p)     = make_float2(acc1[0], acc1[1]);
    *(float2*)(on + 2 * HW + p) = make_float2(acc2[0], acc2[1]);
}

extern "C" void kernel_launch(void* const* d_in, const int* in_sizes, int n_in,
                              void* d_out, int out_size, void* d_ws, size_t ws_size,
                              hipStream_t stream) {
    const float* im1 = (const float*)d_in[0];
    const float* im2 = (const float*)d_in[1];
    const float* C   = (const float*)d_in[2];
    const float* M1  = (const float*)d_in[3];
    const float* M2  = (const float*)d_in[4];
    float* out = (float*)d_out;
    dim3 grid(98, 64);  // 7x14 tiles of 32x16, 64 batch
    vm_kernel<<<grid, 256, 0, stream>>>(im1, im2, C, M1, M2, out);
}

// Round 7
// 170.950 us; speedup vs baseline: 1.1261x; 1.1261x over previous
//
#include <hip/hip_runtime.h>

#define IMG 224
#define HW (IMG * IMG)
#define TILE 32
#define PAD 4
#define REG (TILE + 2 * PAD)   // 40: staged rows/cols per tile
#define RSA 41                 // A-table row stride in float2 units (odd ->
                               //   row steps walk all bank-pairs)
#define TABA (REG * RSA)       // 1640 float2 per image (ch0,ch1 packed)
#define RSB 44                 // B-table row stride in floats (mult of 4 ->
                               //   16B-aligned float4 staging writes)
#define TABB (REG * RSB)       // 1760 floats per image (ch2)

#define NXCD 8
#define NWG  (49 * 64)         // 3136 blocks, 3136 % 8 == 0 -> bijective swizzle

// native clang vector for __builtin_nontemporal_* (HIP_vector_type rejected)
typedef float vfloat4 __attribute__((ext_vector_type(4)));

__global__ __launch_bounds__(256, 4) void vm_kernel(
    const float* __restrict__ im1, const float* __restrict__ im2,
    const float* __restrict__ C, const float* __restrict__ M1,
    const float* __restrict__ M2, float* __restrict__ out)
{
    // Packed-pair tiles: ch0/ch1 as float2 (one ds_read_b64 per tap),
    // ch2 scalar (one ds_read_b32 per tap). 40,320 B -> 4 blocks/CU.
    __shared__ float2 tabA[2 * TABA];
    __shared__ float  tabB[2 * TABB];

    // XCD-aware swizzle: consecutive hardware bids round-robin across the 8
    // XCDs; remap so each XCD owns a CONTIGUOUS logical range = 8 whole batch
    // images (49 tiles each). All halo re-reads of one image then hit that
    // XCD's L2 (per-n working set ~2.9 MB < 4 MB L2).
    const int bid     = blockIdx.x;
    const int logical = (bid & (NXCD - 1)) * (NWG / NXCD) + (bid >> 3);
    const int n       = logical / 49;
    const int tile    = logical - n * 49;  // 0..48

    const int x0   = (tile / 7) * TILE;    // gather col coord (p / 224)
    const int y0   = (tile % 7) * TILE;    // gather row coord (p % 224)
    const int t    = threadIdx.x;
    const int xlo  = x0 - PAD;
    const int ylo  = y0 - PAD;
    const int gbase = xlo + IMG * ylo;     // flat index of tile origin

    const float* i1n = im1 + (size_t)n * 3 * HW;
    const float* i2n = im2 + (size_t)n * 3 * HW;
    const float* Cn  = C  + (size_t)n * 2 * HW;
    const float* M1n = M1 + (size_t)n * HW;
    const float* M2n = M2 + (size_t)n * HW;

    // ---- phase 1: stage both images. Each unit = 4 consecutive pixels of one
    //      row: 3 float4 global loads (one per channel), 4 ds_write_b64 (A)
    //      + 1 ds_write_b128 (B). 400 units per image, coalesced 160B runs.
#pragma unroll
    for (int img = 0; img < 2; ++img) {
        const float* src = img ? i2n : i1n;
        float2* TA = tabA + img * TABA;
        float*  TB = tabB + img * TABB;
#pragma unroll
        for (int k = 0; k < 2; ++k) {
            int e = t + 256 * k;
            if (e < 400) {                  // k=1 partial (t<144)
                int r = e / 10, s = e - r * 10;
                int gi = gbase + IMG * r + 4 * s;
                float4 a, b, c;
                if (gi >= 0 && gi <= HW - 4) {
                    a = *(const float4*)(src + gi);
                    b = *(const float4*)(src + HW + gi);
                    c = *(const float4*)(src + 2 * HW + gi);
                } else {                    // flat-clamp edge rows (rare tiles)
#pragma unroll
                    for (int i = 0; i < 4; ++i) {
                        int g = min(max(gi + i, 0), HW - 1);
                        ((float*)&a)[i] = src[g];
                        ((float*)&b)[i] = src[HW + g];
                        ((float*)&c)[i] = src[2 * HW + g];
                    }
                }
                float2* dA = TA + r * RSA + 4 * s;
                dA[0] = make_float2(a.x, b.x);
                dA[1] = make_float2(a.y, b.y);
                dA[2] = make_float2(a.z, b.z);
                dA[3] = make_float2(a.w, b.w);
                *(float4*)(TB + r * RSB + 4 * s) = c;   // (r*44+4s) % 4 == 0
            }
        }
    }

    // ---- C/M straight to registers as vfloat4 non-temporal (read-once data,
    //      keep L2 capacity for the image halo). Thread owns 4 consecutive ty.
    const int tx  = t >> 3;                // 0..31 (slow coord, p / 224)
    const int ty0 = (t & 7) * 4;           // 0,4,..,28 (fast coord base)
    const int p   = (x0 + tx) * IMG + (y0 + ty0);

    const vfloat4 c0v = __builtin_nontemporal_load((const vfloat4*)(Cn + p));
    const vfloat4 c1v = __builtin_nontemporal_load((const vfloat4*)(Cn + HW + p));
    const vfloat4 m1v = __builtin_nontemporal_load((const vfloat4*)(M1n + p));
    const vfloat4 m2v = __builtin_nontemporal_load((const vfloat4*)(M2n + p));

    __syncthreads();                       // the ONLY barrier

    // ---- phase 2: 4 pixels per thread; per tap one b64 (ch0,ch1) + one b32
    //      (ch2). Output accumulated then stored as 3 float4.
    const float xf = (float)(x0 + tx);
    float acc0[4], acc1[4], acc2[4];

#pragma unroll
    for (int i = 0; i < 4; ++i) {
        const float yf  = (float)(y0 + ty0 + i);
        const float cc0 = c0v[i];
        const float cc1 = c1v[i];
        const float m1i = m1v[i];
        const float m2i = m2v[i];
        float r0c, r1c, r2c;

        {   // +C on im1
            float px = xf + cc0, py = yf + cc1;
            float fx = floorf(px), cx = ceilf(px);
            float fy = floorf(py), cy = ceilf(py);
            float wfx = 1.0f - (px - fx), wcx = 1.0f - (cx - px);
            float wfy = 1.0f - (py - fy), wcy = 1.0f - (cy - py);
            float w0 = wfx * wfy, w1 = wcx * wfy;
            float w2 = wfx * wcy, w3 = wcx * wcy;
            int gx0 = (int)fx, gy0 = (int)fy;
            int dx = (int)cx - gx0, dy = (int)cy - gy0;
            int q0 = gx0 - xlo, r0 = gy0 - ylo;
            int in = (q0 >= 0) & (q0 + dx <= REG - 1) &
                     (r0 >= 0) & (r0 + dy <= REG - 1);
            if (__all(in)) {
                int oA = r0 * RSA + q0;
                int oB = r0 * RSB + q0;
                float2 a0 = tabA[oA],            a1 = tabA[oA + dx];
                float2 a2 = tabA[oA + dy * RSA], a3 = tabA[oA + dx + dy * RSA];
                float  b0 = tabB[oB],            b1 = tabB[oB + dx];
                float  b2 = tabB[oB + dy * RSB], b3 = tabB[oB + dx + dy * RSB];
                r0c = m1i * (w0 * a0.x + w1 * a1.x + w2 * a2.x + w3 * a3.x);
                r1c = m1i * (w0 * a0.y + w1 * a1.y + w2 * a2.y + w3 * a3.y);
                r2c = m1i * (w0 * b0   + w1 * b1   + w2 * b2   + w3 * b3);
            } else {   // rare: displacement beyond PAD -> global clamped gather
                int i0 = min(max(gx0      + IMG * gy0,        0), HW - 1);
                int i1 = min(max(gx0 + dx + IMG * gy0,        0), HW - 1);
                int i2 = min(max(gx0      + IMG * (gy0 + dy), 0), HW - 1);
                int i3 = min(max(gx0 + dx + IMG * (gy0 + dy), 0), HW - 1);
                r0c = m1i * (w0 * i1n[i0] + w1 * i1n[i1] +
                             w2 * i1n[i2] + w3 * i1n[i3]);
                r1c = m1i * (w0 * i1n[HW + i0] + w1 * i1n[HW + i1] +
                             w2 * i1n[HW + i2] + w3 * i1n[HW + i3]);
                r2c = m1i * (w0 * i1n[2 * HW + i0] + w1 * i1n[2 * HW + i1] +
                             w2 * i1n[2 * HW + i2] + w3 * i1n[2 * HW + i3]);
            }
        }
        {   // -C on im2
            float px = xf - cc0, py = yf - cc1;
            float fx = floorf(px), cx = ceilf(px);
            float fy = floorf(py), cy = ceilf(py);
            float wfx = 1.0f - (px - fx), wcx = 1.0f - (cx - px);
            float wfy = 1.0f - (py - fy), wcy = 1.0f - (cy - py);
            float w0 = wfx * wfy, w1 = wcx * wfy;
            float w2 = wfx * wcy, w3 = wcx * wcy;
            int gx0 = (int)fx, gy0 = (int)fy;
            int dx = (int)cx - gx0, dy = (int)cy - gy0;
            int q0 = gx0 - xlo, r0 = gy0 - ylo;
            int in = (q0 >= 0) & (q0 + dx <= REG - 1) &
                     (r0 >= 0) & (r0 + dy <= REG - 1);
            if (__all(in)) {
                const float2* TA = tabA + TABA;
                const float*  TB = tabB + TABB;
                int oA = r0 * RSA + q0;
                int oB = r0 * RSB + q0;
                float2 a0 = TA[oA],            a1 = TA[oA + dx];
                float2 a2 = TA[oA + dy * RSA], a3 = TA[oA + dx + dy * RSA];
                float  b0 = TB[oB],            b1 = TB[oB + dx];
                float  b2 = TB[oB + dy * RSB], b3 = TB[oB + dx + dy * RSB];
                r0c += m2i * (w0 * a0.x + w1 * a1.x + w2 * a2.x + w3 * a3.x);
                r1c += m2i * (w0 * a0.y + w1 * a1.y + w2 * a2.y + w3 * a3.y);
                r2c += m2i * (w0 * b0   + w1 * b1   + w2 * b2   + w3 * b3);
            } else {
                int i0 = min(max(gx0      + IMG * gy0,        0), HW - 1);
                int i1 = min(max(gx0 + dx + IMG * gy0,        0), HW - 1);
                int i2 = min(max(gx0      + IMG * (gy0 + dy), 0), HW - 1);
                int i3 = min(max(gx0 + dx + IMG * (gy0 + dy), 0), HW - 1);
                r0c += m2i * (w0 * i2n[i0] + w1 * i2n[i1] +
                              w2 * i2n[i2] + w3 * i2n[i3]);
                r1c += m2i * (w0 * i2n[HW + i0] + w1 * i2n[HW + i1] +
                              w2 * i2n[HW + i2] + w3 * i2n[HW + i3]);
                r2c += m2i * (w0 * i2n[2 * HW + i0] + w1 * i2n[2 * HW + i1] +
                              w2 * i2n[2 * HW + i2] + w3 * i2n[2 * HW + i3]);
            }
        }
        acc0[i] = r0c; acc1[i] = r1c; acc2[i] = r2c;
    }

    // coalesced non-temporal float4 stores (streaming, don't pollute L2)
    float* on = out + (size_t)n * 3 * HW;
    vfloat4 s0 = {acc0[0], acc0[1], acc0[2], acc0[3]};
    vfloat4 s1 = {acc1[0], acc1[1], acc1[2], acc1[3]};
    vfloat4 s2 = {acc2[0], acc2[1], acc2[2], acc2[3]};
    __builtin_nontemporal_store(s0, (vfloat4*)(on + p));
    __builtin_nontemporal_store(s1, (vfloat4*)(on + HW + p));
    __builtin_nontemporal_store(s2, (vfloat4*)(on + 2 * HW + p));
}

extern "C" void kernel_launch(void* const* d_in, const int* in_sizes, int n_in,
                              void* d_out, int out_size, void* d_ws, size_t ws_size,
                              hipStream_t stream) {
    const float* im1 = (const float*)d_in[0];
    const float* im2 = (const float*)d_in[1];
    const float* C   = (const float*)d_in[2];
    const float* M1  = (const float*)d_in[3];
    const float* M2  = (const float*)d_in[4];
    float* out = (float*)d_out;
    vm_kernel<<<dim3(NWG), 256, 0, stream>>>(im1, im2, C, M1, M2, out);
}